// Round 10
// baseline (657.009 us; speedup 1.0000x reference)
//
#include <hip/hip_runtime.h>

typedef unsigned short u16;
typedef unsigned int   u32;
typedef __attribute__((ext_vector_type(8))) short short8;
typedef __attribute__((ext_vector_type(4))) float f32x4;
typedef __attribute__((ext_vector_type(16))) float f32x16;

constexpr int B_ = 4, S_ = 4096, DIN_ = 2048, DOUT_ = 8192;
constexpr int M_ = B_ * S_;   // 16384
constexpr int N_ = DOUT_;     // 8192
constexpr int K_ = DIN_;      // 2048
constexpr size_t NW_ = (size_t)DOUT_ * DIN_;  // 16,777,216 weights

#define GPTR(p) ((const __attribute__((address_space(1))) void*)(p))
#define LPTR(p) ((__attribute__((address_space(3))) void*)(p))

#define SB0()   __builtin_amdgcn_sched_barrier(0)
#define BAR()   asm volatile("s_barrier" ::: "memory")
#define LGKM0() asm volatile("s_waitcnt lgkmcnt(0)" ::: "memory")
#define VM4()   asm volatile("s_waitcnt vmcnt(4)" ::: "memory")
#define VM0()   asm volatile("s_waitcnt vmcnt(0)" ::: "memory")

__device__ __forceinline__ u16 f2bf(float f) {
    u32 u = __float_as_uint(f);
    u += 0x7fffu + ((u >> 16) & 1u);   // round-to-nearest-even
    return (u16)(u >> 16);
}

// ---------------------------------------------------------------------------
// Pass 1: deterministic fp64 abs-sum partials.
// ---------------------------------------------------------------------------
__global__ __launch_bounds__(256)
void abssum_kernel(const float* __restrict__ w, double* __restrict__ partials)
{
    const int tid = threadIdx.x;
    const float* base = w + (size_t)blockIdx.x * 16384 + tid * 4;
    double s = 0.0;
#pragma unroll
    for (int i = 0; i < 16; ++i) {
        float4 v = *(const float4*)(base + i * 1024);
        s += (double)fabsf(v.x) + (double)fabsf(v.y)
           + (double)fabsf(v.z) + (double)fabsf(v.w);
    }
#pragma unroll
    for (int o = 32; o; o >>= 1) s += __shfl_xor(s, o, 64);
    __shared__ double red[4];
    if ((tid & 63) == 0) red[tid >> 6] = s;
    __syncthreads();
    if (tid == 0) partials[blockIdx.x] = (red[0] + red[1]) + (red[2] + red[3]);
}

__global__ __launch_bounds__(1024)
void finalize_thr(const double* __restrict__ partials, double* __restrict__ thr)
{
    __shared__ double red[1024];
    const int tid = threadIdx.x;
    red[tid] = partials[tid];
    __syncthreads();
    for (int s = 512; s > 0; s >>= 1) {
        if (tid < s) red[tid] += red[tid + s];
        __syncthreads();
    }
    if (tid == 0) *thr = red[0] * (1.0 / (double)NW_);
}

// ---------------------------------------------------------------------------
// Pass 3: ternarize W -> bf16 {-1,0,+1}; fp64 compare (threshold razor-thin).
// ---------------------------------------------------------------------------
__device__ __forceinline__ u16 tern(float w, double thr) {
    return (fabs((double)w) > thr) ? (w > 0.0f ? (u16)0x3F80u : (u16)0xBF80u)
                                   : (u16)0u;
}

__global__ __launch_bounds__(256)
void ternarize_kernel(const float* __restrict__ w, const double* __restrict__ thr_p,
                      u16* __restrict__ wt)
{
    const double thr = *thr_p;
    const size_t i = ((size_t)blockIdx.x * 256 + threadIdx.x) * 4;
    float4 v = *(const float4*)(w + i);
    union { u16 u[4]; uint2 v2; } p;
    p.u[0] = tern(v.x, thr);
    p.u[1] = tern(v.y, thr);
    p.u[2] = tern(v.z, thr);
    p.u[3] = tern(v.w, thr);
    *(uint2*)(wt + i) = p.v2;
}

// ---------------------------------------------------------------------------
// Pass 4: RMSNorm rows of x (fp32) -> bf16 xn.
// ---------------------------------------------------------------------------
__global__ __launch_bounds__(256)
void rmsnorm_kernel(const float* __restrict__ x, const float* __restrict__ gamma,
                    u16* __restrict__ xn)
{
    const int row = blockIdx.x;
    const int tid = threadIdx.x;
    const float* xr = x + (size_t)row * K_;
    float4 a = *(const float4*)(xr + tid * 8);
    float4 b = *(const float4*)(xr + tid * 8 + 4);
    float s = a.x*a.x + a.y*a.y + a.z*a.z + a.w*a.w
            + b.x*b.x + b.y*b.y + b.z*b.z + b.w*b.w;
#pragma unroll
    for (int o = 32; o; o >>= 1) s += __shfl_xor(s, o, 64);
    __shared__ float red[4];
    if ((tid & 63) == 0) red[tid >> 6] = s;
    __syncthreads();
    const float tot = (red[0] + red[1]) + (red[2] + red[3]);
    const float r = rsqrtf(tot * (1.0f / (float)K_) + 1.1920928955078125e-07f);
    float4 g0 = *(const float4*)(gamma + tid * 8);
    float4 g1 = *(const float4*)(gamma + tid * 8 + 4);
    union { u16 u[8]; uint4 v4; } p;
    p.u[0] = f2bf(a.x * r * g0.x);
    p.u[1] = f2bf(a.y * r * g0.y);
    p.u[2] = f2bf(a.z * r * g0.z);
    p.u[3] = f2bf(a.w * r * g0.w);
    p.u[4] = f2bf(b.x * r * g1.x);
    p.u[5] = f2bf(b.y * r * g1.y);
    p.u[6] = f2bf(b.z * r * g1.z);
    p.u[7] = f2bf(b.w * r * g1.w);
    *(uint4*)(xn + (size_t)row * K_ + tid * 8) = p.v4;
}

// ---------------------------------------------------------------------------
// Pass 5: GEMM  C[M,N] = xn[M,K] @ wt[N,K]^T + bias   (bf16 in, fp32 out)
// 256x256 tile, BK=64, 8 waves (2Mx4N). v10 = v9 schedule (byte-identical
// phases/barriers/vmcnt ledger) with MFMA shape swapped to 32x32x16 bf16:
// ceiling 2495 vs 2075 TF (m119/m06), MFMA floor/K-tile 2483 -> 2066 cy/SIMD,
// 4x fewer MFMA instructions. Per wave: 4 mtiles x 2 ntiles of 32x32, acc =
// [4][2] f32x16 (128 regs, same as before). Fragments: A/B lane l holds
// 8 elems at [l&31][(l>>5)*8 + j]; per (tile,kk) one ds_read_b128 — LDS
// traffic unchanged (24 b128/wave/K-tile). Swizzle: slot s=(l>>5)|(kk<<1),
// read at (s ^ (row&7))*16B — every aligned 8-lane group hits 8 distinct
// banks (conflict-free, same property as v9's 16x16 pattern).
// C/D: col=lane&31, row=(reg&3)+8*(reg>>2)+4*(lane>>5)  [m74/m101].
//
//   phase: reads         stage (->target)         MFMA quadrant
//   p0   : a0,b0 (buf0)  B1h0 -> buf1@kt1         Q0 = mt{0,1} x nt0
//   p1   : a1    (buf0)  B1h1 -> buf1@kt1         Q2 = mt{2,3} x nt0
//   p2   : b1    (buf0)  A0h0 -> buf0@kt0+128     Q1 = mt{0,1} x nt1
//   p3   : --            A0h1 -> buf0@kt0+128     Q3 = mt{2,3} x nt1  VM4*
//   p4-p7: same on buf1 (stages B0->buf0@ktn0, A1->buf1@ktn1)         VM4*
// Phase body: [reads|stage] BAR lgkm0 setprio1 8xMFMA setprio0 [VM*] BAR.
// vmcnt ledger identical to v9 (stage counts unchanged): each VM4 retires 8
// loads staged 4-7 phases earlier. Tail: i=15 skips kt+128 stages, p3 VM0.
// ---------------------------------------------------------------------------
__global__ __launch_bounds__(512, 2)
void gemm_bt_kernel(const u16* __restrict__ A, const u16* __restrict__ Bt,
                    const float* __restrict__ bias, float* __restrict__ C)
{
    __shared__ u16 sm[65536];          // 128 KiB: A[2][256][64] | B[2][256][64]
    const char* smc = (const char*)sm;

    const int tid  = threadIdx.x;
    const int lane = tid & 63;
    const int wid  = tid >> 6;
    const int wm   = wid >> 2;         // 0..1
    const int wn   = wid & 3;          // 0..3

    // XCD-aware bijective swizzle: 2048 blocks % 8 == 0
    const int swz = (blockIdx.x & 7) * 256 + (blockIdx.x >> 3);
    const int gm0 = (swz >> 5) * 256;  // 64 M-tiles
    const int gn0 = (swz & 31) * 256;  // 32 N-tiles

    // ---- staging geometry (linear LDS dest, pre-swizzled global source) ----
    const int lr8   = lane >> 3;
    const int cswel = ((lane & 7) ^ lr8) * 8;          // swizzled k-elem offset
    const int rbase = wid * 8 + lr8;                   // 0..63
    const u16* gAr  = A  + (size_t)(gm0 + rbase) * K_ + cswel;
    const u16* gBr  = Bt + (size_t)(gn0 + rbase) * K_ + cswel;
    const u16* gAr2 = gAr + 262144;                    // +128 rows
    const u16* gBr2 = gBr + 262144;

    // one half-tile (128 rows x 64 k) = 2 gload_lds/thread
    auto STAGE = [&](const u16* g, int ldsu, int kt) {
        u16* d = sm + ldsu + wid * 512 + lane * 8;
        const u16* s = g + kt;
        __builtin_amdgcn_global_load_lds(GPTR(s),             LPTR(d),        16, 0, 0);
        __builtin_amdgcn_global_load_lds(GPTR(s + 64 * 2048), LPTR(d + 4096), 16, 0, 0);
    };
    // u16 offsets: A buf0=0, A buf1=16384, B buf0=32768, B buf1=49152 (+8192=h1)

    // ---- read geometry (32x32 fragments) ----
    // lane reads row = base + (lane&31), k-slot s = (lane>>5) | (kk<<1);
    // swizzled byte = ((s ^ (row&7)) << 4) = c0 ^ (kk<<5).
    const int c0 = (((lane >> 5) ^ (lane & 7)) << 4);
    const int rowbyteA = (wm * 128 + (lane & 31)) * 128;
    const int rowbyteB = (wn * 64  + (lane & 31)) * 128;

#define RA(bufr, mt, kk) (*(const short8*)(smc + (bufr)*32768 + rowbyteA + (mt)*4096 + (c0 ^ ((kk) << 5))))
#define RB(bufr, nt, kk) (*(const short8*)(smc + 65536 + (bufr)*32768 + rowbyteB + (nt)*4096 + (c0 ^ ((kk) << 5))))

    f32x16 acc[4][2] = {};
    short8 a0[2][4], a1[2][4], b0[4], b1[4];

    // 8 MFMAs: kk-outer, mt-inner (2 independent acc chains, gap 2)
#define MFMA_BLK(AF, BF, MO, NO)                                                   \
    do {                                                                           \
        _Pragma("unroll") for (int kk = 0; kk < 4; ++kk)                           \
        _Pragma("unroll") for (int m = 0; m < 2; ++m)                              \
            acc[m + MO][NO] = __builtin_amdgcn_mfma_f32_32x32x16_bf16(             \
                AF[m][kk], BF[kk], acc[m + MO][NO], 0, 0, 0);                      \
    } while (0)

#define READ_A0B0(bufr)                                                            \
    do {                                                                           \
        _Pragma("unroll") for (int m = 0; m < 2; ++m)                              \
        _Pragma("unroll") for (int kk = 0; kk < 4; ++kk)                           \
            a0[m][kk] = RA(bufr, m, kk);                                           \
        _Pragma("unroll") for (int kk = 0; kk < 4; ++kk)                           \
            b0[kk] = RB(bufr, 0, kk);                                              \
    } while (0)
#define READ_A1(bufr)                                                              \
    do { _Pragma("unroll") for (int m = 0; m < 2; ++m)                             \
         _Pragma("unroll") for (int kk = 0; kk < 4; ++kk)                          \
            a1[m][kk] = RA(bufr, m + 2, kk); } while (0)
#define READ_B1(bufr)                                                              \
    do { _Pragma("unroll") for (int kk = 0; kk < 4; ++kk)                          \
            b1[kk] = RB(bufr, 1, kk); } while (0)

#define PRIO_MFMA(AF, BF, MO, NO)                                                  \
    do { __builtin_amdgcn_s_setprio(1); MFMA_BLK(AF, BF, MO, NO);                  \
         __builtin_amdgcn_s_setprio(0); } while (0)

    // ---- prologue: buf0 A+B @0 (4 HT), buf1 A @64 (2 HT); retire buf0 ----
    STAGE(gAr,  0,     0);
    STAGE(gAr2, 8192,  0);
    STAGE(gBr,  32768, 0);
    STAGE(gBr2, 40960, 0);
    STAGE(gAr,  16384, 64);
    STAGE(gAr2, 24576, 64);
    VM4(); SB0(); BAR();

    for (int i = 0; i < 16; ++i) {
        const int kt1  = i * 128 + 64;
        const int ktn0 = i * 128 + 128;     // buf0 next K-tile
        const int ktn1 = i * 128 + 192;     // buf1 next K-tile
        const bool f = (i < 15);

        // ---- p0: reads a0,b0(buf0) | stage B1h0@kt1 | Q0(T0) ----
        READ_A0B0(0);
        STAGE(gBr, 49152, kt1);
        SB0(); BAR(); LGKM0(); SB0();
        PRIO_MFMA(a0, b0, 0, 0);
        SB0(); BAR();

        // ---- p1: reads a1(buf0) | stage B1h1@kt1 | Q2(T0) ----
        READ_A1(0);
        STAGE(gBr2, 57344, kt1);
        SB0(); BAR(); LGKM0(); SB0();
        PRIO_MFMA(a1, b0, 2, 0);
        SB0(); BAR();

        // ---- p2: reads b1(buf0) | stage A0h0@ktn0 | Q1(T0) ----
        READ_B1(0);
        if (f) STAGE(gAr, 0, ktn0);
        SB0(); BAR(); LGKM0(); SB0();
        PRIO_MFMA(a0, b1, 0, 1);
        SB0(); BAR();

        // ---- p3: stage A0h1@ktn0 | Q3(T0) | VM4 ----
        if (f) STAGE(gAr2, 8192, ktn0);
        SB0(); BAR();
        PRIO_MFMA(a1, b1, 2, 1);
        SB0();
        if (f) { VM4(); } else { VM0(); }
        SB0(); BAR();

        // ---- p4: reads a0,b0(buf1) | stage B0h0@ktn0 | Q0(T1) ----
        READ_A0B0(1);
        if (f) STAGE(gBr, 32768, ktn0);
        SB0(); BAR(); LGKM0(); SB0();
        PRIO_MFMA(a0, b0, 0, 0);
        SB0(); BAR();

        // ---- p5: reads a1(buf1) | stage B0h1@ktn0 | Q2(T1) ----
        READ_A1(1);
        if (f) STAGE(gBr2, 40960, ktn0);
        SB0(); BAR(); LGKM0(); SB0();
        PRIO_MFMA(a1, b0, 2, 0);
        SB0(); BAR();

        // ---- p6: reads b1(buf1) | stage A1h0@ktn1 | Q1(T1) ----
        READ_B1(1);
        if (f) STAGE(gAr, 16384, ktn1);
        SB0(); BAR(); LGKM0(); SB0();
        PRIO_MFMA(a0, b1, 0, 1);
        SB0(); BAR();

        // ---- p7: stage A1h1@ktn1 | Q3(T1) | VM4 ----
        if (f) STAGE(gAr2, 24576, ktn1);
        SB0(); BAR();
        PRIO_MFMA(a1, b1, 2, 1);
        SB0();
        if (f) { VM4(); }
        SB0(); BAR();
    }

    // ---- epilogue: C/D col=lane&31, row=(reg&3)+8*(reg>>2)+4*(lane>>5) ----
    const int orow_base = gm0 + wm * 128 + 4 * (lane >> 5);
    const int ocol_base = gn0 + wn * 64 + (lane & 31);
#pragma unroll
    for (int nt = 0; nt < 2; ++nt) {
        const float bvv = bias[ocol_base + nt * 32];
#pragma unroll
        for (int mt = 0; mt < 4; ++mt) {
#pragma unroll
            for (int reg = 0; reg < 16; ++reg) {
                const int row = orow_base + mt * 32 + (reg & 3) + 8 * (reg >> 2);
                C[(size_t)row * N_ + (ocol_base + nt * 32)] = acc[mt][nt][reg] + bvv;
            }
        }
    }
#undef RA
#undef RB
#undef MFMA_BLK
#undef READ_A0B0
#undef READ_A1
#undef READ_B1
#undef PRIO_MFMA
}

// ---------------------------------------------------------------------------
// Workspace layout (bytes):
//   [0,8)            : thr (double)
//   [1024, 9216)     : 1024 fp64 partials
//   [16384, +32MiB)  : wt  bf16 [N=8192][K=2048]
//   [wt_end, +64MiB) : xn  bf16 [M=16384][K=2048]
// ---------------------------------------------------------------------------
extern "C" void kernel_launch(void* const* d_in, const int* in_sizes, int n_in,
                              void* d_out, int out_size, void* d_ws, size_t ws_size,
                              hipStream_t stream)
{
    const float* x     = (const float*)d_in[0];
    const float* w     = (const float*)d_in[1];
    const float* bias  = (const float*)d_in[2];
    const float* gamma = (const float*)d_in[3];
    float* out = (float*)d_out;

    char* ws = (char*)d_ws;
    double* thr      = (double*)(ws);
    double* partials = (double*)(ws + 1024);
    u16*    wt       = (u16*)(ws + 16384);
    u16*    xn       = (u16*)(ws + 16384 + NW_ * 2);

    abssum_kernel   <<<1024,  256,  0, stream>>>(w, partials);
    finalize_thr    <<<1,     1024, 0, stream>>>(partials, thr);
    ternarize_kernel<<<16384, 256,  0, stream>>>(w, thr, wt);
    rmsnorm_kernel  <<<M_,    256,  0, stream>>>(x, gamma, xn);
    gemm_bt_kernel  <<<(M_/256)*(N_/256), 512, 0, stream>>>(xn, wt, bias, out);
}

// Round 11
// 403.567 us; speedup vs baseline: 1.6280x; 1.6280x over previous
//
#include <hip/hip_runtime.h>

typedef unsigned short u16;
typedef unsigned int   u32;
typedef unsigned char  u8;
typedef __attribute__((ext_vector_type(4))) int   i32x4;

constexpr int B_ = 4, S_ = 4096, DIN_ = 2048, DOUT_ = 8192;
constexpr int M_ = B_ * S_;   // 16384
constexpr int N_ = DOUT_;     // 8192
constexpr int K_ = DIN_;      // 2048
constexpr size_t NW_ = (size_t)DOUT_ * DIN_;  // 16,777,216 weights

#define GPTR(p) ((const __attribute__((address_space(1))) void*)(p))
#define LPTR(p) ((__attribute__((address_space(3))) void*)(p))

#define SB0()   __builtin_amdgcn_sched_barrier(0)
#define BAR()   asm volatile("s_barrier" ::: "memory")
#define LGKM0() asm volatile("s_waitcnt lgkmcnt(0)" ::: "memory")
#define VM4()   asm volatile("s_waitcnt vmcnt(4)" ::: "memory")
#define VM0()   asm volatile("s_waitcnt vmcnt(0)" ::: "memory")

// ---------------------------------------------------------------------------
// Pass 1: deterministic fp64 abs-sum partials.
// ---------------------------------------------------------------------------
__global__ __launch_bounds__(256)
void abssum_kernel(const float* __restrict__ w, double* __restrict__ partials)
{
    const int tid = threadIdx.x;
    const float* base = w + (size_t)blockIdx.x * 16384 + tid * 4;
    double s = 0.0;
#pragma unroll
    for (int i = 0; i < 16; ++i) {
        float4 v = *(const float4*)(base + i * 1024);
        s += (double)fabsf(v.x) + (double)fabsf(v.y)
           + (double)fabsf(v.z) + (double)fabsf(v.w);
    }
#pragma unroll
    for (int o = 32; o; o >>= 1) s += __shfl_xor(s, o, 64);
    __shared__ double red[4];
    if ((tid & 63) == 0) red[tid >> 6] = s;
    __syncthreads();
    if (tid == 0) partials[blockIdx.x] = (red[0] + red[1]) + (red[2] + red[3]);
}

__global__ __launch_bounds__(1024)
void finalize_thr(const double* __restrict__ partials, double* __restrict__ thr)
{
    __shared__ double red[1024];
    const int tid = threadIdx.x;
    red[tid] = partials[tid];
    __syncthreads();
    for (int s = 512; s > 0; s >>= 1) {
        if (tid < s) red[tid] += red[tid + s];
        __syncthreads();
    }
    if (tid == 0) *thr = red[0] * (1.0 / (double)NW_);
}

// ---------------------------------------------------------------------------
// Pass 3: ternarize W -> i8 {-1,0,+1}; fp64 compare (threshold razor-thin).
// ---------------------------------------------------------------------------
__device__ __forceinline__ int tern(float w, double thr) {
    return (fabs((double)w) > thr) ? (w > 0.0f ? 1 : -1) : 0;
}

__global__ __launch_bounds__(256)
void ternarize_kernel(const float* __restrict__ w, const double* __restrict__ thr_p,
                      signed char* __restrict__ wt)
{
    const double thr = *thr_p;
    const size_t i = ((size_t)blockIdx.x * 256 + threadIdx.x) * 4;
    float4 v = *(const float4*)(w + i);
    union { signed char c[4]; u32 u; } p;
    p.c[0] = (signed char)tern(v.x, thr);
    p.c[1] = (signed char)tern(v.y, thr);
    p.c[2] = (signed char)tern(v.z, thr);
    p.c[3] = (signed char)tern(v.w, thr);
    *(u32*)(wt + i) = p.u;
}

// ---------------------------------------------------------------------------
// Pass 4: RMSNorm rows of x (fp32) -> i8 xn with per-row scale.
// q = round(xn * 127/rowmax); scale[row] = rowmax/127. Matmul vs ternary
// weights is then EXACT in i32; only activation quantization contributes
// error (sigma ~ 0.24 per output, max over 134M outputs ~ 1.4 < 3.48).
// ---------------------------------------------------------------------------
__global__ __launch_bounds__(256)
void rmsnorm_q_kernel(const float* __restrict__ x, const float* __restrict__ gamma,
                      signed char* __restrict__ xn, float* __restrict__ scale)
{
    const int row = blockIdx.x;
    const int tid = threadIdx.x;
    const float* xr = x + (size_t)row * K_;
    float4 a = *(const float4*)(xr + tid * 8);
    float4 b = *(const float4*)(xr + tid * 8 + 4);
    float s = a.x*a.x + a.y*a.y + a.z*a.z + a.w*a.w
            + b.x*b.x + b.y*b.y + b.z*b.z + b.w*b.w;
#pragma unroll
    for (int o = 32; o; o >>= 1) s += __shfl_xor(s, o, 64);
    __shared__ float redsum[4];
    __shared__ float redmax[4];
    if ((tid & 63) == 0) redsum[tid >> 6] = s;
    __syncthreads();
    const float tot = (redsum[0] + redsum[1]) + (redsum[2] + redsum[3]);
    const float r = rsqrtf(tot * (1.0f / (float)K_) + 1.1920928955078125e-07f);
    float4 g0 = *(const float4*)(gamma + tid * 8);
    float4 g1 = *(const float4*)(gamma + tid * 8 + 4);
    float v[8];
    v[0] = a.x * r * g0.x;  v[1] = a.y * r * g0.y;
    v[2] = a.z * r * g0.z;  v[3] = a.w * r * g0.w;
    v[4] = b.x * r * g1.x;  v[5] = b.y * r * g1.y;
    v[6] = b.z * r * g1.z;  v[7] = b.w * r * g1.w;
    float m = 0.0f;
#pragma unroll
    for (int j = 0; j < 8; ++j) m = fmaxf(m, fabsf(v[j]));
#pragma unroll
    for (int o = 32; o; o >>= 1) m = fmaxf(m, __shfl_xor(m, o, 64));
    if ((tid & 63) == 0) redmax[tid >> 6] = m;
    __syncthreads();
    const float rowmax = fmaxf(fmaxf(redmax[0], redmax[1]), fmaxf(redmax[2], redmax[3]));
    const float inv = rowmax > 0.0f ? 127.0f / rowmax : 0.0f;
    union { signed char c[8]; uint2 u; } p;
#pragma unroll
    for (int j = 0; j < 8; ++j) p.c[j] = (signed char)__float2int_rn(v[j] * inv);
    *(uint2*)(xn + (size_t)row * K_ + tid * 8) = p.u;
    if (tid == 0) scale[row] = rowmax * (1.0f / 127.0f);
}

// ---------------------------------------------------------------------------
// Pass 5: GEMM  C[M,N] = scale[m] * (xn_i8[M,K] @ wt_i8[N,K]^T) + bias
// v11 = v9's schedule/LDS-map/swizzle/vmcnt-ledger, BYTE-IDENTICAL (an i8 row
// of BK=128 is 128 B = a bf16 row of BK=64), with mfma_i32_16x16x64_i8:
// 1.9x MFMA rate, half the LDS bytes/k, half the sync events/k. Fragments:
// lane holds 16 contiguous i8 (k = (lane>>4)*16 + j) = one swizzled b128.
// Iteration = 2 K-tiles of 128: buf0@kt0=256i (p0-p3), buf1@kt1=256i+128.
//
//   phase: reads         stage (->target)              MFMA
//   p0   : a0,b0 (buf0)  B1h0 -> buf1@kt1              Q0(T0)
//   p1   : a1    (buf0)  B1h1 -> buf1@kt1              Q2(T0)
//   p2   : b1    (buf0)  A0h0 -> buf0@kt0+256          Q1(T0)
//   p3   : --            A0h1 -> buf0@kt0+256          Q3(T0)  VM4*
//   p4-7 : same on buf1 (B0->buf0@ktn0, A1->buf1@ktn1)         VM4*
// Phase body: [reads|stage] BAR lgkm0 setprio1 16xMFMA setprio0 [VM*] BAR.
// vmcnt ledger identical to v9: each VM4 sees 12 outstanding, retires the 8
// covering the buffer read next, staged 4-7 phases earlier. Tail i=7: VM0.
// LDS bytes: A[2][256][128B] @0, B[2][256][128B] @65536; half-tile +16384.
// ---------------------------------------------------------------------------
__global__ __launch_bounds__(512, 2)
void gemm_bt_kernel(const u8* __restrict__ A, const u8* __restrict__ Bt,
                    const float* __restrict__ bias, const float* __restrict__ scale,
                    float* __restrict__ C)
{
    __shared__ alignas(16) u8 sm[131072];   // 128 KiB
    const char* smc = (const char*)sm;

    const int tid  = threadIdx.x;
    const int lane = tid & 63;
    const int wid  = tid >> 6;
    const int wm   = wid >> 2;         // 0..1
    const int wn   = wid & 3;          // 0..3
    const int hi   = lane >> 4;        // 0..3

    // XCD-aware bijective swizzle: 2048 blocks % 8 == 0
    const int swz = (blockIdx.x & 7) * 256 + (blockIdx.x >> 3);
    const int gm0 = (swz >> 5) * 256;  // 64 M-tiles
    const int gn0 = (swz & 31) * 256;  // 32 N-tiles

    // ---- staging geometry (linear LDS dest, pre-swizzled global source) ----
    // LDS (row r, 16B-slot c) holds global k-slot c ^ (r&7); source k-elem
    // offset = ((lane&7) ^ lr8) * 16 i8.
    const int lr8   = lane >> 3;
    const int cswel = ((lane & 7) ^ lr8) * 16;         // swizzled k-elem offset
    const int rbase = wid * 8 + lr8;                   // 0..63
    const u8* gAr  = A  + (size_t)(gm0 + rbase) * K_ + cswel;
    const u8* gBr  = Bt + (size_t)(gn0 + rbase) * K_ + cswel;
    const u8* gAr2 = gAr + 262144;                     // +128 rows
    const u8* gBr2 = gBr + 262144;

    // one stage call = 128 rows x 128 B = 2 gload_lds(16B)/thread
    auto STAGE = [&](const u8* g, int ldsb, int kt) {
        u8* d = sm + ldsb + wid * 1024 + lane * 16;
        const u8* s = g + kt;
        __builtin_amdgcn_global_load_lds(GPTR(s),             LPTR(d),        16, 0, 0);
        __builtin_amdgcn_global_load_lds(GPTR(s + 64 * 2048), LPTR(d + 8192), 16, 0, 0);
    };

    // ---- read geometry (byte-identical to v9's zero-conflict pattern) ----
    // row = base + (lane&15) (128B rows), slot = hi + 4*kk, read at
    // (slot ^ (row&7))*16 = c0 ^ (kk<<6).
    const int c0 = ((hi ^ (lane & 7)) << 4);
    const int rowbyteA = (wm * 128 + (lane & 15)) * 128;
    const int rowbyteB = (wn * 64  + (lane & 15)) * 128;

#define RA(bufr, m, kk) (*(const i32x4*)(smc + (bufr)*32768 + rowbyteA + (m)*2048 + (c0 ^ ((kk) << 6))))
#define RB(bufr, n, kk) (*(const i32x4*)(smc + 65536 + (bufr)*32768 + rowbyteB + (n)*2048 + (c0 ^ ((kk) << 6))))

    i32x4 acc[8][4] = {};
    i32x4 a0[4][2], a1[4][2], b0[2][2], b1[2][2];

#define MFMA_BLK(AF, BF, MO, NO)                                                   \
    do {                                                                           \
        _Pragma("unroll") for (int kk = 0; kk < 2; ++kk)                           \
        _Pragma("unroll") for (int m = 0; m < 4; ++m)                              \
        _Pragma("unroll") for (int n = 0; n < 2; ++n)                              \
            acc[m + MO][n + NO] = __builtin_amdgcn_mfma_i32_16x16x64_i8(           \
                AF[m][kk], BF[n][kk], acc[m + MO][n + NO], 0, 0, 0);               \
    } while (0)

#define READ_A0B0(bufr)                                                            \
    do {                                                                           \
        _Pragma("unroll") for (int m = 0; m < 4; ++m) {                            \
            a0[m][0] = RA(bufr, m, 0); a0[m][1] = RA(bufr, m, 1); }                \
        _Pragma("unroll") for (int n = 0; n < 2; ++n) {                            \
            b0[n][0] = RB(bufr, n, 0); b0[n][1] = RB(bufr, n, 1); }                \
    } while (0)
#define READ_A1(bufr)                                                              \
    do { _Pragma("unroll") for (int m = 0; m < 4; ++m) {                           \
            a1[m][0] = RA(bufr, m + 4, 0); a1[m][1] = RA(bufr, m + 4, 1); } } while (0)
#define READ_B1(bufr)                                                              \
    do { _Pragma("unroll") for (int n = 0; n < 2; ++n) {                           \
            b1[n][0] = RB(bufr, n + 2, 0); b1[n][1] = RB(bufr, n + 2, 1); } } while (0)

#define PRIO_MFMA(AF, BF, MO, NO)                                                  \
    do { __builtin_amdgcn_s_setprio(1); MFMA_BLK(AF, BF, MO, NO);                  \
         __builtin_amdgcn_s_setprio(0); } while (0)

    // ---- prologue: buf0 A+B @0, buf1 A @128; retire buf0 ----
    STAGE(gAr,  0,     0);
    STAGE(gAr2, 16384, 0);
    STAGE(gBr,  65536, 0);
    STAGE(gBr2, 81920, 0);
    STAGE(gAr,  32768, 128);
    STAGE(gAr2, 49152, 128);
    VM4(); SB0(); BAR();

    for (int i = 0; i < 8; ++i) {
        const int kt1  = i * 256 + 128;
        const int ktn0 = i * 256 + 256;     // buf0 next K-tile
        const int ktn1 = i * 256 + 384;     // buf1 next K-tile
        const bool f = (i < 7);

        // ---- p0: reads a0,b0(buf0) | stage B1h0@kt1 | Q0(T0) ----
        READ_A0B0(0);
        STAGE(gBr, 98304, kt1);
        SB0(); BAR(); LGKM0(); SB0();
        PRIO_MFMA(a0, b0, 0, 0);
        SB0(); BAR();

        // ---- p1: reads a1(buf0) | stage B1h1@kt1 | Q2(T0) ----
        READ_A1(0);
        STAGE(gBr2, 114688, kt1);
        SB0(); BAR(); LGKM0(); SB0();
        PRIO_MFMA(a1, b0, 4, 0);
        SB0(); BAR();

        // ---- p2: reads b1(buf0) | stage A0h0@ktn0 | Q1(T0) ----
        READ_B1(0);
        if (f) STAGE(gAr, 0, ktn0);
        SB0(); BAR(); LGKM0(); SB0();
        PRIO_MFMA(a0, b1, 0, 2);
        SB0(); BAR();

        // ---- p3: stage A0h1@ktn0 | Q3(T0) | VM4 ----
        if (f) STAGE(gAr2, 16384, ktn0);
        SB0(); BAR();
        PRIO_MFMA(a1, b1, 4, 2);
        SB0();
        if (f) { VM4(); } else { VM0(); }
        SB0(); BAR();

        // ---- p4: reads a0,b0(buf1) | stage B0h0@ktn0 | Q0(T1) ----
        READ_A0B0(1);
        if (f) STAGE(gBr, 65536, ktn0);
        SB0(); BAR(); LGKM0(); SB0();
        PRIO_MFMA(a0, b0, 0, 0);
        SB0(); BAR();

        // ---- p5: reads a1(buf1) | stage B0h1@ktn0 | Q2(T1) ----
        READ_A1(1);
        if (f) STAGE(gBr2, 81920, ktn0);
        SB0(); BAR(); LGKM0(); SB0();
        PRIO_MFMA(a1, b0, 4, 0);
        SB0(); BAR();

        // ---- p6: reads b1(buf1) | stage A1h0@ktn1 | Q1(T1) ----
        READ_B1(1);
        if (f) STAGE(gAr, 32768, ktn1);
        SB0(); BAR(); LGKM0(); SB0();
        PRIO_MFMA(a0, b1, 0, 2);
        SB0(); BAR();

        // ---- p7: stage A1h1@ktn1 | Q3(T1) | VM4 ----
        if (f) STAGE(gAr2, 49152, ktn1);
        SB0(); BAR();
        PRIO_MFMA(a1, b1, 4, 2);
        SB0();
        if (f) { VM4(); }
        SB0(); BAR();
    }

    // ---- epilogue: C/D col=lane&15, row=hi*4+i; dequant + bias ----
    const int orow0 = gm0 + wm * 128 + hi * 4;
    const int ocol0 = gn0 + wn * 64 + (lane & 15);
    float bv[4];
#pragma unroll
    for (int n = 0; n < 4; ++n) bv[n] = bias[ocol0 + n * 16];
#pragma unroll
    for (int m = 0; m < 8; ++m) {
#pragma unroll
        for (int ri = 0; ri < 4; ++ri) {
            const int row = orow0 + m * 16 + ri;
            const float sc = scale[row];
#pragma unroll
            for (int n = 0; n < 4; ++n) {
                C[(size_t)row * N_ + (ocol0 + n * 16)] = (float)acc[m][n][ri] * sc + bv[n];
            }
        }
    }
#undef RA
#undef RB
#undef MFMA_BLK
#undef READ_A0B0
#undef READ_A1
#undef READ_B1
#undef PRIO_MFMA
}

// ---------------------------------------------------------------------------
// Workspace layout (bytes):
//   [0,8)                    : thr (double)
//   [1024, 9216)             : 1024 fp64 partials
//   [16384, +16MiB)          : wt    i8 [N=8192][K=2048]
//   [+16MiB, +48MiB)         : xn    i8 [M=16384][K=2048]
//   [+48MiB, +48MiB+64KiB)   : scale f32 [M]
// ---------------------------------------------------------------------------
extern "C" void kernel_launch(void* const* d_in, const int* in_sizes, int n_in,
                              void* d_out, int out_size, void* d_ws, size_t ws_size,
                              hipStream_t stream)
{
    const float* x     = (const float*)d_in[0];
    const float* w     = (const float*)d_in[1];
    const float* bias  = (const float*)d_in[2];
    const float* gamma = (const float*)d_in[3];
    float* out = (float*)d_out;

    char* ws = (char*)d_ws;
    double*      thr      = (double*)(ws);
    double*      partials = (double*)(ws + 1024);
    signed char* wt       = (signed char*)(ws + 16384);
    signed char* xn       = (signed char*)(ws + 16384 + NW_);
    float*       scale    = (float*)(ws + 16384 + NW_ + (size_t)M_ * K_);

    abssum_kernel   <<<1024,  256,  0, stream>>>(w, partials);
    finalize_thr    <<<1,     1024, 0, stream>>>(partials, thr);
    ternarize_kernel<<<16384, 256,  0, stream>>>(w, thr, wt);
    rmsnorm_q_kernel<<<M_,    256,  0, stream>>>(x, gamma, xn, scale);
    gemm_bt_kernel  <<<(M_/256)*(N_/256), 512, 0, stream>>>((const u8*)xn, (const u8*)wt, bias, scale, out);
}